// Round 5
// baseline (31.722 us; speedup 1.0000x reference)
//
#include <hip/hip_runtime.h>
#include <math.h>

// LIF router: I = seq @ W^T + b ; U <- min(beta*U + I_t, 1) over T ; softmax(U_T).
//
// Exploits:
//  1) min(.,1) is 1-Lipschitz, beta=0.9 -> only last KTAIL=128 steps matter
//     (error <= |U|*0.9^128 ~ 1.4e-5; threshold 1.3e-3, 90x margin).
//  2) U -> min(a*U+b, c) closed under composition -> scan parallelizes over
//     16-step chunks (8 per batch), folded in-kernel.
//  3) Split-bf16 MFMA: x = hi+lo, A*B ~ AhBh + AlBh + AhBl (err ~1e-5).
//  4) SINGLE dispatch: batch-local flag handshake (agent-scope atomics) lets
//     the ch==7 workgroup fold all 8 chunk tuples + softmax. Replay-safe via
//     sentinel reset; deadlock-free (128 wgs < 256 CUs, co-resident).
//  5) W loads issued as the OLDEST vmem ops so the split-bf16 W conversion
//     overlaps the seq-stage HBM flight (vmcnt retires in order).

typedef __attribute__((ext_vector_type(8))) short short8;
typedef __attribute__((ext_vector_type(4))) float f32x4;

#define BETA 0.9f
constexpr int Bn = 16, Tn = 4096, Dn = 1024, En = 64;
constexpr int KTAIL = 128, CHK = 16, NCHK = KTAIL / CHK;   // 8 chunks/batch
constexpr float A16 = 0.18530201888518416f;                // 0.9^16
constexpr unsigned READY = 0x5A5A1234u;                    // != 0x0, != 0xAAAAAAAA
constexpr unsigned SENT  = 0x81818181u;

__device__ __forceinline__ unsigned short f2bf(float x) {  // f32 -> bf16 RNE
    unsigned u = __float_as_uint(x);
    u += 0x7fffu + ((u >> 16) & 1u);
    return (unsigned short)(u >> 16);
}

// ---------------------------------------------------------------------------
// ONE kernel: stage + W-convert + split-bf16 MFMA + compose + cross-wg fold.
// Grid 128 = (b, chunk); 512 thr = 8 waves, wave wv owns d in [wv*128,+128).
// ---------------------------------------------------------------------------
__global__ __launch_bounds__(512, 1) void lif_one(const float4* __restrict__ seq4,
                                                  const float* __restrict__ W,
                                                  const float* __restrict__ bias,
                                                  float2* __restrict__ tup,
                                                  unsigned* __restrict__ flags,
                                                  float* __restrict__ out) {
    __shared__ float4 sA[4096];  // 16 rows x 1024 d f32 = 64 KB
    const int bid = blockIdx.x;
    const int b = bid >> 3, ch = bid & 7;
    const int t = threadIdx.x, lane = t & 63;
    const int wv = __builtin_amdgcn_readfirstlane(t >> 6);
    const int m = lane & 15, g = lane >> 4;
    const int t0 = Tn - KTAIL + ch * CHK;
    const float4* tile = seq4 + (size_t)(b * Tn + t0) * (Dn / 4);

    // ---- (oldest vmem) W gather: e = nt*16+m, d = ks*32+g*8+j, ks=wv*4+kk
    float4 wtmp[4][4][2];
#pragma unroll
    for (int kk = 0; kk < 4; ++kk)
#pragma unroll
        for (int nt = 0; nt < 4; ++nt) {
            const float* wp = W + (size_t)(nt * 16 + m) * Dn + (wv * 4 + kk) * 32 + g * 8;
            wtmp[kk][nt][0] = *(const float4*)wp;
            wtmp[kk][nt][1] = *(const float4*)(wp + 4);
        }

    // ---- stage loads (in flight while W converts below)
    float4 vbuf[8];
#pragma unroll
    for (int i = 0; i < 8; ++i) vbuf[i] = tile[i * 512 + t];

#define CVT(dh, dl, slot, val)                                              \
    { const float xv = (val); const unsigned short h = f2bf(xv);            \
      dh[slot] = (short)h;                                                  \
      dl[slot] = (short)f2bf(xv - __uint_as_float((unsigned)h << 16)); }

    // ---- W split-bf16 conversion (waits only W loads; stage still in flight)
    short8 WH[4][4], WL[4][4];
#pragma unroll
    for (int kk = 0; kk < 4; ++kk)
#pragma unroll
        for (int nt = 0; nt < 4; ++nt) {
            const float4 w0 = wtmp[kk][nt][0], w1 = wtmp[kk][nt][1];
            short8 bh, bl;
            CVT(bh, bl, 0, w0.x) CVT(bh, bl, 1, w0.y) CVT(bh, bl, 2, w0.z) CVT(bh, bl, 3, w0.w)
            CVT(bh, bl, 4, w1.x) CVT(bh, bl, 5, w1.y) CVT(bh, bl, 6, w1.z) CVT(bh, bl, 7, w1.w)
            WH[kk][nt] = bh; WL[kk][nt] = bl;
        }

    // ---- LDS store with 16B-granular XOR swizzle (verified rounds 3/4)
#pragma unroll
    for (int i = 0; i < 8; ++i) {
        const int u = i * 512 + t, row = u >> 8, cp = u & 255;
        sA[(row << 8) | (cp ^ (row & 7))] = vbuf[i];
    }
    __syncthreads();

    f32x4 acc[4];
#pragma unroll
    for (int i = 0; i < 4; ++i) {
        acc[i][0] = 0.f; acc[i][1] = 0.f; acc[i][2] = 0.f; acc[i][3] = 0.f;
    }

#pragma unroll
    for (int kk = 0; kk < 4; ++kk) {
        const int ks = wv * 4 + kk;
        const int c0 = ks * 8 + g * 2;
        const float4 a0 = sA[(m << 8) | (c0 ^ (m & 7))];
        const float4 a1 = sA[(m << 8) | ((c0 + 1) ^ (m & 7))];
        short8 ah, al;
        CVT(ah, al, 0, a0.x) CVT(ah, al, 1, a0.y) CVT(ah, al, 2, a0.z) CVT(ah, al, 3, a0.w)
        CVT(ah, al, 4, a1.x) CVT(ah, al, 5, a1.y) CVT(ah, al, 6, a1.z) CVT(ah, al, 7, a1.w)
#pragma unroll
        for (int nt = 0; nt < 4; ++nt) {
            acc[nt] = __builtin_amdgcn_mfma_f32_16x16x32_bf16(ah, WH[kk][nt], acc[nt], 0, 0, 0);
            acc[nt] = __builtin_amdgcn_mfma_f32_16x16x32_bf16(al, WH[kk][nt], acc[nt], 0, 0, 0);
            acc[nt] = __builtin_amdgcn_mfma_f32_16x16x32_bf16(ah, WL[kk][nt], acc[nt], 0, 0, 0);
        }
    }
#undef CVT
    __syncthreads();  // sA frag reads done -> safe to alias

    // C-frag (m89-verified): lane holds D[r=g*4+q][e16=m]
    float* sC = (float*)sA;  // [wave][16 r][64 e], 32 KB
#pragma unroll
    for (int nt = 0; nt < 4; ++nt)
#pragma unroll
        for (int q = 0; q < 4; ++q)
            sC[(wv * 16 + g * 4 + q) * 64 + nt * 16 + m] = acc[nt][q];
    __syncthreads();

    // 8-way K-partial reduce + bias
    float* sI = (float*)sA + 8192;  // [16 r][64 e], 4 KB
#pragma unroll
    for (int h = 0; h < 2; ++h) {
        const int idx = h * 512 + t, r = idx >> 6, e = idx & 63;
        float s = bias[e];
#pragma unroll
        for (int w = 0; w < 8; ++w) s += sC[(w * 16 + r) * 64 + e];
        sI[r * 64 + e] = s;
    }
    __syncthreads();

    // compose this chunk's min-affine tuple (lane = e)
    float bb = 0.f, cc = 1e30f;
    if (t < 64) {
#pragma unroll
        for (int r = 0; r < CHK; ++r) {
            const float I = sI[r * 64 + t];
            bb = fmaf(BETA, bb, I);
            cc = fminf(fmaf(BETA, cc, I), 1.0f);
        }
    }

    if (ch != 7) {
        // publish tuple via agent-scope 64-bit atomic (coherence point, no
        // cross-XCD L2 staleness), then release the READY flag.
        if (t < 64) {
            float2 v = make_float2(bb, cc);
            unsigned long long u;
            __builtin_memcpy(&u, &v, 8);
            __hip_atomic_store((unsigned long long*)&tup[(b * NCHK + ch) * En + t],
                               u, __ATOMIC_RELAXED, __HIP_MEMORY_SCOPE_AGENT);
        }
        __syncthreads();
        if (t == 0) {
            __threadfence();
            __hip_atomic_store(&flags[b * 7 + ch], READY,
                               __ATOMIC_RELEASE, __HIP_MEMORY_SCOPE_AGENT);
        }
        return;
    }

    // ---- finisher (ch==7): wait for the 7 sibling tuples
    if (t == 0) {
#pragma unroll 1
        for (int c = 0; c < 7; ++c)
            while (__hip_atomic_load(&flags[b * 7 + c], __ATOMIC_ACQUIRE,
                                     __HIP_MEMORY_SCOPE_AGENT) != READY)
                __builtin_amdgcn_s_sleep(2);
        __threadfence();
    }
    __syncthreads();

    if (t < 64) {
        float Bv = 0.f, Cv = 1e30f;
#pragma unroll 1
        for (int c = 0; c < 7; ++c) {
            unsigned long long u = __hip_atomic_load(
                (unsigned long long*)&tup[(b * NCHK + c) * En + t],
                __ATOMIC_RELAXED, __HIP_MEMORY_SCOPE_AGENT);
            float2 gg;
            __builtin_memcpy(&gg, &u, 8);
            Bv = fmaf(A16, Bv, gg.x);
            Cv = fminf(fmaf(A16, Cv, gg.x), gg.y);
        }
        Bv = fmaf(A16, Bv, bb);                 // own chunk (ch==7), from regs
        Cv = fminf(fmaf(A16, Cv, bb), cc);
        const float U = fminf(Bv, Cv);

        float mx = U;
#pragma unroll
        for (int mask = 32; mask; mask >>= 1)
            mx = fmaxf(mx, __shfl_xor(mx, mask, 64));
        const float ex = expf(U - mx);
        float s = ex;
#pragma unroll
        for (int mask = 32; mask; mask >>= 1)
            s += __shfl_xor(s, mask, 64);
        out[b * En + t] = ex / s;
    }

    // reset flags to sentinel for the next graph replay
    if (t == 0) {
#pragma unroll
        for (int c = 0; c < 7; ++c)
            __hip_atomic_store(&flags[b * 7 + c], SENT,
                               __ATOMIC_RELAXED, __HIP_MEMORY_SCOPE_AGENT);
    }
}

extern "C" void kernel_launch(void* const* d_in, const int* in_sizes, int n_in,
                              void* d_out, int out_size, void* d_ws, size_t ws_size,
                              hipStream_t stream) {
    const float4* seq4 = (const float4*)d_in[0];
    const float* W = (const float*)d_in[1];
    const float* bias = (const float*)d_in[2];
    float* out = (float*)d_out;

    float2* tup = (float2*)d_ws;                           // 16*8*64*8 = 64 KB
    unsigned* flags = (unsigned*)((char*)d_ws + 65536);    // 16*7*4 = 448 B

    lif_one<<<dim3(Bn * NCHK), dim3(512), 0, stream>>>(seq4, W, bias, tup, flags, out);
}

// Round 6
// 29.495 us; speedup vs baseline: 1.0755x; 1.0755x over previous
//
#include <hip/hip_runtime.h>
#include <math.h>

// LIF router: I = seq @ W^T + b ; U <- min(beta*U + I_t, 1) over T ; softmax(U_T).
//
// Exploits:
//  1) min(.,1) is 1-Lipschitz, beta=0.9 -> only last KTAIL=128 steps matter
//     (error <= |U|*0.9^128 ~ 1.4e-5; threshold 1.3e-3, ~90x margin).
//  2) U -> min(a*U+b, c) closed under composition -> scan parallelizes over
//     16-step chunks (8 per batch), folded in-kernel.
//  3) Split-bf16 MFMA: x = hi+lo, A*B ~ AhBh + AlBh + AhBl (err ~1e-5).
//  4) SINGLE dispatch: batch-local flag handshake (agent-scope atomics); the
//     ch==7 wg folds all 8 tuples + softmax. Replay-safe via sentinel reset.
//  5) Round-6 fix: depth-1 W pipeline (whc/wlc current + wn next) instead of
//     round 5's full prefetch -- peak live VGPR ~150 vs ~300+ (which spilled
//     to scratch and cost +15 us). W kk=0 still issued as the OLDEST vmem ops
//     so its convert overlaps the seq-stage HBM flight.

typedef __attribute__((ext_vector_type(8))) short short8;
typedef __attribute__((ext_vector_type(4))) float f32x4;

#define BETA 0.9f
constexpr int Bn = 16, Tn = 4096, Dn = 1024, En = 64;
constexpr int KTAIL = 128, CHK = 16, NCHK = KTAIL / CHK;   // 8 chunks/batch
constexpr float A16 = 0.18530201888518416f;                // 0.9^16
constexpr unsigned READY = 0x5A5A1234u;                    // != 0x0, != 0xAAAAAAAA
constexpr unsigned SENT  = 0x81818181u;

__device__ __forceinline__ unsigned short f2bf(float x) {  // f32 -> bf16 RNE
    unsigned u = __float_as_uint(x);
    u += 0x7fffu + ((u >> 16) & 1u);
    return (unsigned short)(u >> 16);
}

#define CVT(dh, dl, slot, val)                                              \
    { const float xv = (val); const unsigned short h = f2bf(xv);            \
      dh[slot] = (short)h;                                                  \
      dl[slot] = (short)f2bf(xv - __uint_as_float((unsigned)h << 16)); }

// ---------------------------------------------------------------------------
// ONE kernel: stage + W-convert + split-bf16 MFMA + compose + cross-wg fold.
// Grid 128 = (b, chunk); 512 thr = 8 waves, wave wv owns d in [wv*128,+128).
// ---------------------------------------------------------------------------
__global__ __launch_bounds__(512, 1) void lif_one(const float4* __restrict__ seq4,
                                                  const float* __restrict__ W,
                                                  const float* __restrict__ bias,
                                                  float2* __restrict__ tup,
                                                  unsigned* __restrict__ flags,
                                                  float* __restrict__ out) {
    __shared__ float4 sA[4096];  // 16 rows x 1024 d f32 = 64 KB
    const int bid = blockIdx.x;
    const int b = bid >> 3, ch = bid & 7;
    const int t = threadIdx.x, lane = t & 63;
    const int wv = __builtin_amdgcn_readfirstlane(t >> 6);
    const int m = lane & 15, g = lane >> 4;
    const int t0 = Tn - KTAIL + ch * CHK;
    const float4* tile = seq4 + (size_t)(b * Tn + t0) * (Dn / 4);
    // B-frag source: e = nt*16+m, d = ks*32+g*8+j  (layout verified r3/r4)
    const float* wb = W + (size_t)m * Dn + g * 8;

    // ---- (oldest vmem) W loads for kk=0 only: 8 float4 = 32 VGPR
    float4 wn[8];
#pragma unroll
    for (int nt = 0; nt < 4; ++nt) {
        const float* wp = wb + nt * 16 * Dn + (wv * 4) * 32;
        wn[nt * 2]     = *(const float4*)wp;
        wn[nt * 2 + 1] = *(const float4*)(wp + 4);
    }

    // ---- stage loads (still in flight while W kk=0 converts below)
    float4 vbuf[8];
#pragma unroll
    for (int i = 0; i < 8; ++i) vbuf[i] = tile[i * 512 + t];

    // ---- convert W kk=0 (waits only the W loads)
    short8 whc[4], wlc[4];
#pragma unroll
    for (int nt = 0; nt < 4; ++nt) {
        const float4 w0 = wn[nt * 2], w1 = wn[nt * 2 + 1];
        short8 bh, bl;
        CVT(bh, bl, 0, w0.x) CVT(bh, bl, 1, w0.y) CVT(bh, bl, 2, w0.z) CVT(bh, bl, 3, w0.w)
        CVT(bh, bl, 4, w1.x) CVT(bh, bl, 5, w1.y) CVT(bh, bl, 6, w1.z) CVT(bh, bl, 7, w1.w)
        whc[nt] = bh; wlc[nt] = bl;
    }

    // ---- LDS store with 16B-granular XOR swizzle (verified rounds 3-5)
#pragma unroll
    for (int i = 0; i < 8; ++i) {
        const int u = i * 512 + t, row = u >> 8, cp = u & 255;
        sA[(row << 8) | (cp ^ (row & 7))] = vbuf[i];
    }
    __syncthreads();

    f32x4 acc[4];
#pragma unroll
    for (int i = 0; i < 4; ++i) {
        acc[i][0] = 0.f; acc[i][1] = 0.f; acc[i][2] = 0.f; acc[i][3] = 0.f;
    }

#pragma unroll
    for (int kk = 0; kk < 4; ++kk) {
        const int ks = wv * 4 + kk;
        // prefetch next kk's W (in flight across this iteration's VALU+MFMA)
        float4 wnx[8];
        if (kk < 3) {
#pragma unroll
            for (int nt = 0; nt < 4; ++nt) {
                const float* wp = wb + nt * 16 * Dn + (ks + 1) * 32;
                wnx[nt * 2]     = *(const float4*)wp;
                wnx[nt * 2 + 1] = *(const float4*)(wp + 4);
            }
        }
        // A-frag from LDS: row=m, k=g*8+j
        const int c0 = ks * 8 + g * 2;
        const float4 a0 = sA[(m << 8) | (c0 ^ (m & 7))];
        const float4 a1 = sA[(m << 8) | ((c0 + 1) ^ (m & 7))];
        short8 ah, al;
        CVT(ah, al, 0, a0.x) CVT(ah, al, 1, a0.y) CVT(ah, al, 2, a0.z) CVT(ah, al, 3, a0.w)
        CVT(ah, al, 4, a1.x) CVT(ah, al, 5, a1.y) CVT(ah, al, 6, a1.z) CVT(ah, al, 7, a1.w)
#pragma unroll
        for (int nt = 0; nt < 4; ++nt) {
            acc[nt] = __builtin_amdgcn_mfma_f32_16x16x32_bf16(ah, whc[nt], acc[nt], 0, 0, 0);
            acc[nt] = __builtin_amdgcn_mfma_f32_16x16x32_bf16(al, whc[nt], acc[nt], 0, 0, 0);
            acc[nt] = __builtin_amdgcn_mfma_f32_16x16x32_bf16(ah, wlc[nt], acc[nt], 0, 0, 0);
        }
        // rotate: convert prefetched W into current
        if (kk < 3) {
#pragma unroll
            for (int nt = 0; nt < 4; ++nt) {
                const float4 w0 = wnx[nt * 2], w1 = wnx[nt * 2 + 1];
                short8 bh, bl;
                CVT(bh, bl, 0, w0.x) CVT(bh, bl, 1, w0.y) CVT(bh, bl, 2, w0.z) CVT(bh, bl, 3, w0.w)
                CVT(bh, bl, 4, w1.x) CVT(bh, bl, 5, w1.y) CVT(bh, bl, 6, w1.z) CVT(bh, bl, 7, w1.w)
                whc[nt] = bh; wlc[nt] = bl;
            }
        }
    }
    __syncthreads();  // sA frag reads done -> safe to alias

    // C-frag (m89-verified): lane holds D[r=g*4+q][e16=m]
    float* sC = (float*)sA;  // [wave][16 r][64 e], 32 KB
#pragma unroll
    for (int nt = 0; nt < 4; ++nt)
#pragma unroll
        for (int q = 0; q < 4; ++q)
            sC[(wv * 16 + g * 4 + q) * 64 + nt * 16 + m] = acc[nt][q];
    __syncthreads();

    // 8-way K-partial reduce + bias
    float* sI = (float*)sA + 8192;  // [16 r][64 e], 4 KB
#pragma unroll
    for (int h = 0; h < 2; ++h) {
        const int idx = h * 512 + t, r = idx >> 6, e = idx & 63;
        float s = bias[e];
#pragma unroll
        for (int w = 0; w < 8; ++w) s += sC[(w * 16 + r) * 64 + e];
        sI[r * 64 + e] = s;
    }
    __syncthreads();

    // compose this chunk's min-affine tuple (lane = e)
    float bb = 0.f, cc = 1e30f;
    if (t < 64) {
#pragma unroll
        for (int r = 0; r < CHK; ++r) {
            const float I = sI[r * 64 + t];
            bb = fmaf(BETA, bb, I);
            cc = fminf(fmaf(BETA, cc, I), 1.0f);
        }
    }

    if (ch != 7) {
        // publish tuple (agent-scope 64-bit atomics -> coherence point), then
        // release the READY flag.
        if (t < 64) {
            float2 v = make_float2(bb, cc);
            unsigned long long u;
            __builtin_memcpy(&u, &v, 8);
            __hip_atomic_store((unsigned long long*)&tup[(b * NCHK + ch) * En + t],
                               u, __ATOMIC_RELAXED, __HIP_MEMORY_SCOPE_AGENT);
        }
        __syncthreads();
        if (t == 0) {
            __threadfence();
            __hip_atomic_store(&flags[b * 7 + ch], READY,
                               __ATOMIC_RELEASE, __HIP_MEMORY_SCOPE_AGENT);
        }
        return;
    }

    // ---- finisher (ch==7): wait for the 7 sibling tuples
    if (t == 0) {
#pragma unroll 1
        for (int c = 0; c < 7; ++c)
            while (__hip_atomic_load(&flags[b * 7 + c], __ATOMIC_ACQUIRE,
                                     __HIP_MEMORY_SCOPE_AGENT) != READY)
                __builtin_amdgcn_s_sleep(2);
        __threadfence();
    }
    __syncthreads();

    if (t < 64) {
        float Bv = 0.f, Cv = 1e30f;
#pragma unroll 1
        for (int c = 0; c < 7; ++c) {
            unsigned long long u = __hip_atomic_load(
                (unsigned long long*)&tup[(b * NCHK + c) * En + t],
                __ATOMIC_RELAXED, __HIP_MEMORY_SCOPE_AGENT);
            float2 gg;
            __builtin_memcpy(&gg, &u, 8);
            Bv = fmaf(A16, Bv, gg.x);
            Cv = fminf(fmaf(A16, Cv, gg.x), gg.y);
        }
        Bv = fmaf(A16, Bv, bb);                 // own chunk (ch==7), from regs
        Cv = fminf(fmaf(A16, Cv, bb), cc);
        const float U = fminf(Bv, Cv);

        float mx = U;
#pragma unroll
        for (int mask = 32; mask; mask >>= 1)
            mx = fmaxf(mx, __shfl_xor(mx, mask, 64));
        const float ex = expf(U - mx);
        float s = ex;
#pragma unroll
        for (int mask = 32; mask; mask >>= 1)
            s += __shfl_xor(s, mask, 64);
        out[b * En + t] = ex / s;
    }

    // reset flags to sentinel for the next graph replay
    if (t == 0) {
#pragma unroll
        for (int c = 0; c < 7; ++c)
            __hip_atomic_store(&flags[b * 7 + c], SENT,
                               __ATOMIC_RELAXED, __HIP_MEMORY_SCOPE_AGENT);
    }
}
#undef CVT

extern "C" void kernel_launch(void* const* d_in, const int* in_sizes, int n_in,
                              void* d_out, int out_size, void* d_ws, size_t ws_size,
                              hipStream_t stream) {
    const float4* seq4 = (const float4*)d_in[0];
    const float* W = (const float*)d_in[1];
    const float* bias = (const float*)d_in[2];
    float* out = (float*)d_out;

    float2* tup = (float2*)d_ws;                           // 16*8*64*8 = 64 KB
    unsigned* flags = (unsigned*)((char*)d_ws + 65536);    // 16*7*4 = 448 B

    lif_one<<<dim3(Bn * NCHK), dim3(512), 0, stream>>>(seq4, W, bias, tup, flags, out);
}

// Round 7
// 17.283 us; speedup vs baseline: 1.8354x; 1.7066x over previous
//
#include <hip/hip_runtime.h>
#include <math.h>

// LIF router: I = seq @ W^T + b ; U <- min(beta*U + I_t, 1) over T ; softmax(U_T).
//
// Exploits:
//  1) min(.,1) is 1-Lipschitz, beta=0.9 -> only last KTAIL=128 steps matter
//     (error <= |U|*0.9^128 ~ 1.4e-5; threshold 1.3e-3, ~90x margin).
//  2) U -> min(a*U+b, c) closed under composition -> scan parallelizes over
//     16-step chunks (8 per batch), folded in-kernel.
//  3) Split-bf16 MFMA: x = hi+lo, A*B ~ AhBh + AlBh + AhBl (err ~1e-5).
//  4) SINGLE dispatch, FABRIC-ATOMIC handshake (round-7 fix): rounds 5/6 used
//     acquire-polls + __threadfence -> one cache-invalidate per poll iteration
//     across all XCDs = L2 invalidate storm while producers streamed seq/W
//     (+13 us). Now every cross-wg op is a device-scope atomic RMW executed at
//     the coherence point: atomicExch to publish, atomicAdd(p,0) to read.
//     ZERO cache-maintenance instructions. Replay-safe via SENT reset.
//  5) Depth-1 W pipeline (r6): peak live VGPR ~150, no scratch spills; W kk=0
//     issued as the oldest vmem ops so its convert overlaps the seq staging.

typedef __attribute__((ext_vector_type(8))) short short8;
typedef __attribute__((ext_vector_type(4))) float f32x4;

#define BETA 0.9f
constexpr int Bn = 16, Tn = 4096, Dn = 1024, En = 64;
constexpr int KTAIL = 128, CHK = 16, NCHK = KTAIL / CHK;   // 8 chunks/batch
constexpr float A16 = 0.18530201888518416f;                // 0.9^16
constexpr unsigned READY = 0x5A5A1234u;                    // != 0, != 0xAAAAAAAA
constexpr unsigned SENT  = 0x81818181u;

__device__ __forceinline__ unsigned short f2bf(float x) {  // f32 -> bf16 RNE
    unsigned u = __float_as_uint(x);
    u += 0x7fffu + ((u >> 16) & 1u);
    return (unsigned short)(u >> 16);
}

#define CVT(dh, dl, slot, val)                                              \
    { const float xv = (val); const unsigned short h = f2bf(xv);            \
      dh[slot] = (short)h;                                                  \
      dl[slot] = (short)f2bf(xv - __uint_as_float((unsigned)h << 16)); }

// ---------------------------------------------------------------------------
// ONE kernel: stage + W-convert + split-bf16 MFMA + compose + cross-wg fold.
// Grid 128 = (b, chunk); 512 thr = 8 waves, wave wv owns d in [wv*128,+128).
// ---------------------------------------------------------------------------
__global__ __launch_bounds__(512, 1) void lif_one(const float4* __restrict__ seq4,
                                                  const float* __restrict__ W,
                                                  const float* __restrict__ bias,
                                                  float2* __restrict__ tup,
                                                  unsigned* __restrict__ flags,
                                                  float* __restrict__ out) {
    __shared__ float4 sA[4096];  // 16 rows x 1024 d f32 = 64 KB
    const int bid = blockIdx.x;
    const int b = bid >> 3, ch = bid & 7;
    const int t = threadIdx.x, lane = t & 63;
    const int wv = __builtin_amdgcn_readfirstlane(t >> 6);
    const int m = lane & 15, g = lane >> 4;
    const int t0 = Tn - KTAIL + ch * CHK;
    const float4* tile = seq4 + (size_t)(b * Tn + t0) * (Dn / 4);
    // B-frag source: e = nt*16+m, d = ks*32+g*8+j  (layout verified r3-r6)
    const float* wb = W + (size_t)m * Dn + g * 8;

    // ---- (oldest vmem) W loads for kk=0 only: 8 float4 = 32 VGPR
    float4 wn[8];
#pragma unroll
    for (int nt = 0; nt < 4; ++nt) {
        const float* wp = wb + nt * 16 * Dn + (wv * 4) * 32;
        wn[nt * 2]     = *(const float4*)wp;
        wn[nt * 2 + 1] = *(const float4*)(wp + 4);
    }

    // ---- stage loads (still in flight while W kk=0 converts below)
    float4 vbuf[8];
#pragma unroll
    for (int i = 0; i < 8; ++i) vbuf[i] = tile[i * 512 + t];

    // ---- convert W kk=0 (waits only the W loads)
    short8 whc[4], wlc[4];
#pragma unroll
    for (int nt = 0; nt < 4; ++nt) {
        const float4 w0 = wn[nt * 2], w1 = wn[nt * 2 + 1];
        short8 bh, bl;
        CVT(bh, bl, 0, w0.x) CVT(bh, bl, 1, w0.y) CVT(bh, bl, 2, w0.z) CVT(bh, bl, 3, w0.w)
        CVT(bh, bl, 4, w1.x) CVT(bh, bl, 5, w1.y) CVT(bh, bl, 6, w1.z) CVT(bh, bl, 7, w1.w)
        whc[nt] = bh; wlc[nt] = bl;
    }

    // ---- LDS store with 16B-granular XOR swizzle (verified rounds 3-6)
#pragma unroll
    for (int i = 0; i < 8; ++i) {
        const int u = i * 512 + t, row = u >> 8, cp = u & 255;
        sA[(row << 8) | (cp ^ (row & 7))] = vbuf[i];
    }
    __syncthreads();

    f32x4 acc[4];
#pragma unroll
    for (int i = 0; i < 4; ++i) {
        acc[i][0] = 0.f; acc[i][1] = 0.f; acc[i][2] = 0.f; acc[i][3] = 0.f;
    }

#pragma unroll
    for (int kk = 0; kk < 4; ++kk) {
        const int ks = wv * 4 + kk;
        // prefetch next kk's W (in flight across this iteration's VALU+MFMA)
        float4 wnx[8];
        if (kk < 3) {
#pragma unroll
            for (int nt = 0; nt < 4; ++nt) {
                const float* wp = wb + nt * 16 * Dn + (ks + 1) * 32;
                wnx[nt * 2]     = *(const float4*)wp;
                wnx[nt * 2 + 1] = *(const float4*)(wp + 4);
            }
        }
        // A-frag from LDS: row=m, k=g*8+j
        const int c0 = ks * 8 + g * 2;
        const float4 a0 = sA[(m << 8) | (c0 ^ (m & 7))];
        const float4 a1 = sA[(m << 8) | ((c0 + 1) ^ (m & 7))];
        short8 ah, al;
        CVT(ah, al, 0, a0.x) CVT(ah, al, 1, a0.y) CVT(ah, al, 2, a0.z) CVT(ah, al, 3, a0.w)
        CVT(ah, al, 4, a1.x) CVT(ah, al, 5, a1.y) CVT(ah, al, 6, a1.z) CVT(ah, al, 7, a1.w)
#pragma unroll
        for (int nt = 0; nt < 4; ++nt) {
            acc[nt] = __builtin_amdgcn_mfma_f32_16x16x32_bf16(ah, whc[nt], acc[nt], 0, 0, 0);
            acc[nt] = __builtin_amdgcn_mfma_f32_16x16x32_bf16(al, whc[nt], acc[nt], 0, 0, 0);
            acc[nt] = __builtin_amdgcn_mfma_f32_16x16x32_bf16(ah, wlc[nt], acc[nt], 0, 0, 0);
        }
        // rotate: convert prefetched W into current
        if (kk < 3) {
#pragma unroll
            for (int nt = 0; nt < 4; ++nt) {
                const float4 w0 = wnx[nt * 2], w1 = wnx[nt * 2 + 1];
                short8 bh, bl;
                CVT(bh, bl, 0, w0.x) CVT(bh, bl, 1, w0.y) CVT(bh, bl, 2, w0.z) CVT(bh, bl, 3, w0.w)
                CVT(bh, bl, 4, w1.x) CVT(bh, bl, 5, w1.y) CVT(bh, bl, 6, w1.z) CVT(bh, bl, 7, w1.w)
                whc[nt] = bh; wlc[nt] = bl;
            }
        }
    }
    __syncthreads();  // sA frag reads done -> safe to alias

    // C-frag (m89-verified): lane holds D[r=g*4+q][e16=m]
    float* sC = (float*)sA;  // [wave][16 r][64 e], 32 KB
#pragma unroll
    for (int nt = 0; nt < 4; ++nt)
#pragma unroll
        for (int q = 0; q < 4; ++q)
            sC[(wv * 16 + g * 4 + q) * 64 + nt * 16 + m] = acc[nt][q];
    __syncthreads();

    // 8-way K-partial reduce + bias
    float* sI = (float*)sA + 8192;  // [16 r][64 e], 4 KB
#pragma unroll
    for (int h = 0; h < 2; ++h) {
        const int idx = h * 512 + t, r = idx >> 6, e = idx & 63;
        float s = bias[e];
#pragma unroll
        for (int w = 0; w < 8; ++w) s += sC[(w * 16 + r) * 64 + e];
        sI[r * 64 + e] = s;
    }
    __syncthreads();

    // compose this chunk's min-affine tuple (lane = e)
    float bb = 0.f, cc = 1e30f;
    if (t < 64) {
#pragma unroll
        for (int r = 0; r < CHK; ++r) {
            const float I = sI[r * 64 + t];
            bb = fmaf(BETA, bb, I);
            cc = fminf(fmaf(BETA, cc, I), 1.0f);
        }
    }

    if (ch != 7) {
        // publish tuple via device-scope atomic RMW (coherence point; no
        // cache-maintenance ops anywhere on this path).
        if (t < 64) {
            float2 v = make_float2(bb, cc);
            unsigned long long u;
            __builtin_memcpy(&u, &v, 8);
            atomicExch((unsigned long long*)&tup[(b * NCHK + ch) * En + t], u);
        }
        __syncthreads();  // barrier drain: wave-0 tup atomics retired at fabric
        if (t == 0) {
            asm volatile("s_waitcnt vmcnt(0)" ::: "memory");
            atomicExch(&flags[b * 8 + ch], READY);
        }
        return;
    }

    // ---- finisher (ch==7): lanes 0..6 poll sibling flags via fabric RMW-read
    if (t < 7) {
        while (atomicAdd(&flags[b * 8 + t], 0u) != READY)
            __builtin_amdgcn_s_sleep(8);
    }
    __syncthreads();

    if (t < 64) {
        // fetch all 7 tuples (independent RMW-reads, issued back-to-back ->
        // one fabric latency), then fold in chronological chunk order.
        unsigned long long uv[7];
#pragma unroll
        for (int c = 0; c < 7; ++c)
            uv[c] = atomicAdd((unsigned long long*)&tup[(b * NCHK + c) * En + t], 0ull);
        float Bv = 0.f, Cv = 1e30f;
#pragma unroll
        for (int c = 0; c < 7; ++c) {
            float2 gg;
            __builtin_memcpy(&gg, &uv[c], 8);
            Bv = fmaf(A16, Bv, gg.x);
            Cv = fminf(fmaf(A16, Cv, gg.x), gg.y);
        }
        Bv = fmaf(A16, Bv, bb);                 // own chunk (ch==7), from regs
        Cv = fminf(fmaf(A16, Cv, bb), cc);
        const float U = fminf(Bv, Cv);

        float mx = U;
#pragma unroll
        for (int mask = 32; mask; mask >>= 1)
            mx = fmaxf(mx, __shfl_xor(mx, mask, 64));
        const float ex = expf(U - mx);
        float s = ex;
#pragma unroll
        for (int mask = 32; mask; mask >>= 1)
            s += __shfl_xor(s, mask, 64);
        out[b * En + t] = ex / s;
    }

    // reset flags for the next graph replay (SENT != READY)
    if (t < 7) atomicExch(&flags[b * 8 + t], SENT);
}
#undef CVT

extern "C" void kernel_launch(void* const* d_in, const int* in_sizes, int n_in,
                              void* d_out, int out_size, void* d_ws, size_t ws_size,
                              hipStream_t stream) {
    const float4* seq4 = (const float4*)d_in[0];
    const float* W = (const float*)d_in[1];
    const float* bias = (const float*)d_in[2];
    float* out = (float*)d_out;

    float2* tup = (float2*)d_ws;                           // 16*8*64*8 = 64 KB
    unsigned* flags = (unsigned*)((char*)d_ws + 65536);    // 16*8*4 = 512 B

    lif_one<<<dim3(Bn * NCHK), dim3(512), 0, stream>>>(seq4, W, bias, tup, flags, out);
}

// Round 8
// 16.737 us; speedup vs baseline: 1.8952x; 1.0326x over previous
//
#include <hip/hip_runtime.h>
#include <math.h>

// LIF router: I = seq @ W^T + b ; U <- min(beta*U + I_t, 1) over T ; softmax(U_T).
//
// Exploits:
//  1) min(.,1) is 1-Lipschitz, beta=0.9 -> only last KTAIL=128 steps matter
//     (error <= |U|*0.9^128 ~ 1.4e-5; threshold 1.3e-3, ~90x margin).
//  2) U -> min(a*U+b, c) closed under composition -> scan parallelizes over
//     8-step chunks (16 per batch), folded in-kernel.
//  3) Split-bf16 MFMA: x = hi+lo, A*B ~ AhBh + AlBh + AhBl (err ~1e-5).
//  4) SINGLE dispatch, FABRIC-ATOMIC handshake (validated r7): all cross-wg
//     ops are device-scope atomic RMWs at the coherence point (atomicExch to
//     publish, atomicAdd(p,0) to read). Zero cache-maintenance instructions
//     (r5/r6's acquire+fence path cost ~12 us in L2 invalidate storms).
//  5) Round-8: CHK 16->8, grid 128->256 wgs = all CUs busy, per-wg critical
//     path halved (stage 32 KB). MFMA A-row = m&7 (rows 8-15 duplicate; same
//     LDS address for lanes m/m+8 -> broadcast, free; dup rows not stored).
//  6) Depth-1 W pipeline (r6): peak live VGPR ~150, no scratch spills; W kk=0
//     issued as the oldest vmem ops so its convert overlaps the seq staging.

typedef __attribute__((ext_vector_type(8))) short short8;
typedef __attribute__((ext_vector_type(4))) float f32x4;

#define BETA 0.9f
constexpr int Bn = 16, Tn = 4096, Dn = 1024, En = 64;
constexpr int KTAIL = 128, CHK = 8, NCHK = KTAIL / CHK;    // 16 chunks/batch
constexpr float A8 = 0.43046721f;                          // 0.9^8
constexpr unsigned READY = 0x5A5A1234u;                    // != 0, != 0xAAAAAAAA
constexpr unsigned SENT  = 0x81818181u;

__device__ __forceinline__ unsigned short f2bf(float x) {  // f32 -> bf16 RNE
    unsigned u = __float_as_uint(x);
    u += 0x7fffu + ((u >> 16) & 1u);
    return (unsigned short)(u >> 16);
}

#define CVT(dh, dl, slot, val)                                              \
    { const float xv = (val); const unsigned short h = f2bf(xv);            \
      dh[slot] = (short)h;                                                  \
      dl[slot] = (short)f2bf(xv - __uint_as_float((unsigned)h << 16)); }

// ---------------------------------------------------------------------------
// ONE kernel: stage + W-convert + split-bf16 MFMA + compose + cross-wg fold.
// Grid 256 = (b, chunk); 512 thr = 8 waves, wave wv owns d in [wv*128,+128).
// ---------------------------------------------------------------------------
__global__ __launch_bounds__(512, 1) void lif_one(const float4* __restrict__ seq4,
                                                  const float* __restrict__ W,
                                                  const float* __restrict__ bias,
                                                  float2* __restrict__ tup,
                                                  unsigned* __restrict__ flags,
                                                  float* __restrict__ out) {
    __shared__ float4 sA[2048];  // 8 rows x 1024 d f32 = 32 KB
    const int bid = blockIdx.x;
    const int b = bid >> 4, ch = bid & 15;
    const int t = threadIdx.x, lane = t & 63;
    const int wv = __builtin_amdgcn_readfirstlane(t >> 6);
    const int m = lane & 15, g = lane >> 4;
    const int mr = m & 7;                     // A-row (8 valid rows, dup x2)
    const int t0 = Tn - KTAIL + ch * CHK;
    const float4* tile = seq4 + (size_t)(b * Tn + t0) * (Dn / 4);
    // B-frag source: e = nt*16+m, d = ks*32+g*8+j  (layout verified r3-r7)
    const float* wb = W + (size_t)m * Dn + g * 8;

    // ---- (oldest vmem) W loads for kk=0 only: 8 float4 = 32 VGPR
    float4 wn[8];
#pragma unroll
    for (int nt = 0; nt < 4; ++nt) {
        const float* wp = wb + nt * 16 * Dn + (wv * 4) * 32;
        wn[nt * 2]     = *(const float4*)wp;
        wn[nt * 2 + 1] = *(const float4*)(wp + 4);
    }

    // ---- stage loads (still in flight while W kk=0 converts below)
    float4 vbuf[4];
#pragma unroll
    for (int i = 0; i < 4; ++i) vbuf[i] = tile[i * 512 + t];

    // ---- convert W kk=0 (waits only the W loads)
    short8 whc[4], wlc[4];
#pragma unroll
    for (int nt = 0; nt < 4; ++nt) {
        const float4 w0 = wn[nt * 2], w1 = wn[nt * 2 + 1];
        short8 bh, bl;
        CVT(bh, bl, 0, w0.x) CVT(bh, bl, 1, w0.y) CVT(bh, bl, 2, w0.z) CVT(bh, bl, 3, w0.w)
        CVT(bh, bl, 4, w1.x) CVT(bh, bl, 5, w1.y) CVT(bh, bl, 6, w1.z) CVT(bh, bl, 7, w1.w)
        whc[nt] = bh; wlc[nt] = bl;
    }

    // ---- LDS store with 16B-granular XOR swizzle (verified rounds 3-7)
#pragma unroll
    for (int i = 0; i < 4; ++i) {
        const int u = i * 512 + t, row = u >> 8, cp = u & 255;
        sA[(row << 8) | (cp ^ (row & 7))] = vbuf[i];
    }
    __syncthreads();

    f32x4 acc[4];
#pragma unroll
    for (int i = 0; i < 4; ++i) {
        acc[i][0] = 0.f; acc[i][1] = 0.f; acc[i][2] = 0.f; acc[i][3] = 0.f;
    }

#pragma unroll
    for (int kk = 0; kk < 4; ++kk) {
        const int ks = wv * 4 + kk;
        // prefetch next kk's W (in flight across this iteration's VALU+MFMA)
        float4 wnx[8];
        if (kk < 3) {
#pragma unroll
            for (int nt = 0; nt < 4; ++nt) {
                const float* wp = wb + nt * 16 * Dn + (ks + 1) * 32;
                wnx[nt * 2]     = *(const float4*)wp;
                wnx[nt * 2 + 1] = *(const float4*)(wp + 4);
            }
        }
        // A-frag from LDS: row=mr (lanes m and m+8 broadcast-share), k=g*8+j
        const int c0 = ks * 8 + g * 2;
        const float4 a0 = sA[(mr << 8) | (c0 ^ mr)];
        const float4 a1 = sA[(mr << 8) | ((c0 + 1) ^ mr)];
        short8 ah, al;
        CVT(ah, al, 0, a0.x) CVT(ah, al, 1, a0.y) CVT(ah, al, 2, a0.z) CVT(ah, al, 3, a0.w)
        CVT(ah, al, 4, a1.x) CVT(ah, al, 5, a1.y) CVT(ah, al, 6, a1.z) CVT(ah, al, 7, a1.w)
#pragma unroll
        for (int nt = 0; nt < 4; ++nt) {
            acc[nt] = __builtin_amdgcn_mfma_f32_16x16x32_bf16(ah, whc[nt], acc[nt], 0, 0, 0);
            acc[nt] = __builtin_amdgcn_mfma_f32_16x16x32_bf16(al, whc[nt], acc[nt], 0, 0, 0);
            acc[nt] = __builtin_amdgcn_mfma_f32_16x16x32_bf16(ah, wlc[nt], acc[nt], 0, 0, 0);
        }
        // rotate: convert prefetched W into current
        if (kk < 3) {
#pragma unroll
            for (int nt = 0; nt < 4; ++nt) {
                const float4 w0 = wnx[nt * 2], w1 = wnx[nt * 2 + 1];
                short8 bh, bl;
                CVT(bh, bl, 0, w0.x) CVT(bh, bl, 1, w0.y) CVT(bh, bl, 2, w0.z) CVT(bh, bl, 3, w0.w)
                CVT(bh, bl, 4, w1.x) CVT(bh, bl, 5, w1.y) CVT(bh, bl, 6, w1.z) CVT(bh, bl, 7, w1.w)
                whc[nt] = bh; wlc[nt] = bl;
            }
        }
    }
    __syncthreads();  // sA frag reads done -> safe to alias

    // C-frag (m89-verified): lane holds D[r=g*4+q][e16=m]; rows 8-15 are
    // duplicates of 0-7 (A-row = m&7) -> only g<2 lanes store.
    float* sC = (float*)sA;  // [8 wv][8 r][64 e] = 16 KB
    if (g < 2) {
#pragma unroll
        for (int nt = 0; nt < 4; ++nt)
#pragma unroll
            for (int q = 0; q < 4; ++q)
                sC[(wv * 8 + g * 4 + q) * 64 + nt * 16 + m] = acc[nt][q];
    }
    __syncthreads();

    // 8-way K-partial reduce + bias: 512 cells / 512 threads
    float* sI = (float*)sA + 4096;  // [8 r][64 e], 2 KB
    {
        const int r = t >> 6, e = t & 63;
        float s = bias[e];
#pragma unroll
        for (int w = 0; w < 8; ++w) s += sC[(w * 8 + r) * 64 + e];
        sI[r * 64 + e] = s;
    }
    __syncthreads();

    // compose this chunk's min-affine tuple (lane = e)
    float bb = 0.f, cc = 1e30f;
    if (t < 64) {
#pragma unroll
        for (int r = 0; r < CHK; ++r) {
            const float I = sI[r * 64 + t];
            bb = fmaf(BETA, bb, I);
            cc = fminf(fmaf(BETA, cc, I), 1.0f);
        }
    }

    if (ch != 15) {
        // publish tuple via device-scope atomic RMW (coherence point; no
        // cache-maintenance ops anywhere on this path).
        if (t < 64) {
            float2 v = make_float2(bb, cc);
            unsigned long long u;
            __builtin_memcpy(&u, &v, 8);
            atomicExch((unsigned long long*)&tup[(b * NCHK + ch) * En + t], u);
        }
        __syncthreads();  // barrier drain: wave-0 tup atomics retired at fabric
        if (t == 0) {
            asm volatile("s_waitcnt vmcnt(0)" ::: "memory");
            atomicExch(&flags[b * 16 + ch], READY);
        }
        return;
    }

    // ---- finisher (ch==15): lanes 0..14 poll sibling flags via fabric RMW
    if (t < 15) {
        while (atomicAdd(&flags[b * 16 + t], 0u) != READY)
            __builtin_amdgcn_s_sleep(8);
    }
    __syncthreads();

    if (t < 64) {
        // fetch all 15 tuples (independent RMW-reads, back-to-back -> one
        // fabric latency), then fold in chronological chunk order.
        unsigned long long uv[15];
#pragma unroll
        for (int c = 0; c < 15; ++c)
            uv[c] = atomicAdd((unsigned long long*)&tup[(b * NCHK + c) * En + t], 0ull);
        float Bv = 0.f, Cv = 1e30f;
#pragma unroll
        for (int c = 0; c < 15; ++c) {
            float2 gg;
            __builtin_memcpy(&gg, &uv[c], 8);
            Bv = fmaf(A8, Bv, gg.x);
            Cv = fminf(fmaf(A8, Cv, gg.x), gg.y);
        }
        Bv = fmaf(A8, Bv, bb);                  // own chunk (ch==15), from regs
        Cv = fminf(fmaf(A8, Cv, bb), cc);
        const float U = fminf(Bv, Cv);

        float mx = U;
#pragma unroll
        for (int mask = 32; mask; mask >>= 1)
            mx = fmaxf(mx, __shfl_xor(mx, mask, 64));
        const float ex = expf(U - mx);
        float s = ex;
#pragma unroll
        for (int mask = 32; mask; mask >>= 1)
            s += __shfl_xor(s, mask, 64);
        out[b * En + t] = ex / s;
    }

    // reset flags for the next graph replay (SENT != READY)
    if (t < 15) atomicExch(&flags[b * 16 + t], SENT);
}
#undef CVT

extern "C" void kernel_launch(void* const* d_in, const int* in_sizes, int n_in,
                              void* d_out, int out_size, void* d_ws, size_t ws_size,
                              hipStream_t stream) {
    const float4* seq4 = (const float4*)d_in[0];
    const float* W = (const float*)d_in[1];
    const float* bias = (const float*)d_in[2];
    float* out = (float*)d_out;

    float2* tup = (float2*)d_ws;                           // 16*16*64*8 = 128 KB
    unsigned* flags = (unsigned*)((char*)d_ws + 131072);   // 16*16*4 = 1 KB

    lif_one<<<dim3(Bn * NCHK), dim3(512), 0, stream>>>(seq4, W, bias, tup, flags, out);
}